// Round 1
// baseline (136.802 us; speedup 1.0000x reference)
//
#include <hip/hip_runtime.h>

constexpr int WIDTH  = 96;
constexpr int HEIGHT = 72;
constexpr int NPTS   = WIDTH * HEIGHT;   // 6912
constexpr int TILE   = 256;
constexpr int NT     = NPTS / TILE;      // 27 (exact)
constexpr int NBLK   = NT * NT;          // 729

// exp(-0.1*d) = exp2(d * KEXP)
constexpr float KEXP = -0.14426950408889634f;  // -0.1 * log2(e)

// invK = [[0,0,1],[1/48,0,-1],[0,1/36,-1]] ; grid col(u,v) = (1, u/48-1, v/36-1)

__device__ __forceinline__ void point_data(
    int idx,
    const float* __restrict__ depth1, const float* __restrict__ depth2,
    const float* __restrict__ img1,   const float* __restrict__ img2,
    const float R[12], const float G[12], float o[18])
{
    const int u = idx % WIDTH;
    const int v = idx / WIDTH;
    const float gy = (float)u * (1.0f / 48.0f) - 1.0f;
    const float gz = (float)v * (1.0f / 36.0f) - 1.0f;
    const float d1 = depth1[idx];
    const float d2 = depth2[idx];
    // back-projected points
    const float x1 = d1, y1 = d1 * gy, z1 = d1 * gz;
    const float x2 = d2, y2 = d2 * gy, z2 = d2 * gz;
    // pose1_2 transform
    const float xt = R[0] * x2 + R[1] * y2 + R[2]  * z2 + R[3];
    const float yt = R[4] * x2 + R[5] * y2 + R[6]  * z2 + R[7];
    const float zt = R[8] * x2 + R[9] * y2 + R[10] * z2 + R[11];
    // pose1_2_gt transform
    const float xg = G[0] * x2 + G[1] * y2 + G[2]  * z2 + G[3];
    const float yg = G[4] * x2 + G[5] * y2 + G[6]  * z2 + G[7];
    const float zg = G[8] * x2 + G[9] * y2 + G[10] * z2 + G[11];

    o[0] = x1; o[1] = y1; o[2] = z1;
    o[3] = xt; o[4] = yt; o[5] = zt;
    o[6] = xg; o[7] = yg; o[8] = zg;
    o[9]  = img1[idx];
    o[10] = img1[NPTS + idx];
    o[11] = img1[2 * NPTS + idx];
    o[12] = img2[idx];
    o[13] = img2[NPTS + idx];
    o[14] = img2[2 * NPTS + idx];
    o[15] = x1 * x1 + y1 * y1 + z1 * z1;   // |xyz1|^2
    o[16] = xt * xt + yt * yt + zt * zt;   // |xyz2_t|^2
    o[17] = xg * xg + yg * yg + zg * zg;   // |xyz2_tgt|^2
}

__global__ __launch_bounds__(TILE) void pair_kernel(
    const float* __restrict__ depth1, const float* __restrict__ depth2,
    const float* __restrict__ pose,   const float* __restrict__ img1,
    const float* __restrict__ img2,   const float* __restrict__ poseg,
    double* __restrict__ partials)
{
    __shared__ float sm[TILE][18];
    __shared__ double red[4][5];

    const int t  = threadIdx.x;
    const int bn = blockIdx.x % NT;
    const int bm = blockIdx.x / NT;

    // poses (wave-uniform -> SGPRs). pose is 4x4 row-major; rows 0..2 used.
    float R[12], G[12];
#pragma unroll
    for (int i = 0; i < 12; ++i) { R[i] = pose[i]; G[i] = poseg[i]; }

    // stage m-tile into LDS
    {
        float o[18];
        point_data(bm * TILE + t, depth1, depth2, img1, img2, R, G, o);
#pragma unroll
        for (int k = 0; k < 18; ++k) sm[t][k] = o[k];
    }

    // n-point state in registers
    float a[18];
    point_data(bn * TILE + t, depth1, depth2, img1, img2, R, G, a);

    __syncthreads();

    float s0 = 0.f, s1 = 0.f, s2 = 0.f, s3 = 0.f, s4 = 0.f;

#pragma unroll 4
    for (int m = 0; m < TILE; ++m) {
        const float* b = sm[m];   // wave-uniform address -> LDS broadcast

        // geometric dots
        const float dot11 = a[0] * b[0] + a[1] * b[1] + a[2] * b[2]; // xyz1 . xyz1'
        const float dot22 = a[3] * b[3] + a[4] * b[4] + a[5] * b[5]; // xyz2t . xyz2t'
        const float dot12 = a[0] * b[3] + a[1] * b[4] + a[2] * b[5]; // xyz1 . xyz2t'
        const float dotgg = a[6] * b[6] + a[7] * b[7] + a[8] * b[8]; // xyz2g . xyz2g'
        const float dot1g = a[0] * b[6] + a[1] * b[7] + a[2] * b[8]; // xyz1 . xyz2g'

        // feature grams
        const float g11 = a[9]  * b[9]  + a[10] * b[10] + a[11] * b[11];
        const float g22 = a[12] * b[12] + a[13] * b[13] + a[14] * b[14];
        const float g12 = a[9]  * b[12] + a[10] * b[13] + a[11] * b[14];

        const float e11 = exp2f((a[15] + b[15] - 2.f * dot11) * KEXP);
        const float e22 = exp2f((a[16] + b[16] - 2.f * dot22) * KEXP);
        const float e12 = exp2f((a[15] + b[16] - 2.f * dot12) * KEXP);
        const float egg = exp2f((a[17] + b[17] - 2.f * dotgg) * KEXP);
        const float e1g = exp2f((a[15] + b[17] - 2.f * dot1g) * KEXP);

        s0 += e11 * g11;   // f1_f1
        s1 += e22 * g22;   // f2_f2
        s2 += e12 * g12;   // f1_f2
        s3 += egg * g22;   // f2_f2_gt
        s4 += e1g * g12;   // f1_f2_gt
    }

    // wave (64-lane) reduction
#pragma unroll
    for (int off = 32; off > 0; off >>= 1) {
        s0 += __shfl_down(s0, off);
        s1 += __shfl_down(s1, off);
        s2 += __shfl_down(s2, off);
        s3 += __shfl_down(s3, off);
        s4 += __shfl_down(s4, off);
    }
    const int wave = t >> 6, lane = t & 63;
    if (lane == 0) {
        red[wave][0] = (double)s0; red[wave][1] = (double)s1;
        red[wave][2] = (double)s2; red[wave][3] = (double)s3;
        red[wave][4] = (double)s4;
    }
    __syncthreads();
    if (t == 0) {
        double* out = partials + (size_t)blockIdx.x * 5;
#pragma unroll
        for (int c = 0; c < 5; ++c)
            out[c] = red[0][c] + red[1][c] + red[2][c] + red[3][c];
    }
}

__global__ void finalize_kernel(const double* __restrict__ partials,
                                float* __restrict__ out)
{
    double l0 = 0, l1 = 0, l2 = 0, l3 = 0, l4 = 0;
    for (int b = threadIdx.x; b < NBLK; b += 64) {
        const double* p = partials + (size_t)b * 5;
        l0 += p[0]; l1 += p[1]; l2 += p[2]; l3 += p[3]; l4 += p[4];
    }
#pragma unroll
    for (int off = 32; off > 0; off >>= 1) {
        l0 += __shfl_down(l0, off);
        l1 += __shfl_down(l1, off);
        l2 += __shfl_down(l2, off);
        l3 += __shfl_down(l3, off);
        l4 += __shfl_down(l4, off);
    }
    if (threadIdx.x == 0) {
        const double num = l0 + l1 - 2.0 * l2;
        const double den = l0 + l3 - 2.0 * l4;
        out[0] = (float)(num / den);
    }
}

extern "C" void kernel_launch(void* const* d_in, const int* in_sizes, int n_in,
                              void* d_out, int out_size, void* d_ws, size_t ws_size,
                              hipStream_t stream)
{
    const float* depth1 = (const float*)d_in[0];
    const float* depth2 = (const float*)d_in[1];
    const float* pose   = (const float*)d_in[2];
    const float* img1   = (const float*)d_in[3];
    const float* img2   = (const float*)d_in[4];
    const float* poseg  = (const float*)d_in[5];

    double* partials = (double*)d_ws;   // NBLK*5 doubles = ~29 KB

    pair_kernel<<<NBLK, TILE, 0, stream>>>(depth1, depth2, pose, img1, img2,
                                           poseg, partials);
    finalize_kernel<<<1, 64, 0, stream>>>(partials, (float*)d_out);
}

// Round 2
// 72.831 us; speedup vs baseline: 1.8784x; 1.8784x over previous
//
#include <hip/hip_runtime.h>

typedef float v2f __attribute__((ext_vector_type(2)));

constexpr int WIDTH  = 96;
constexpr int HEIGHT = 72;
constexpr int NPTS   = WIDTH * HEIGHT;   // 6912
constexpr int BLOCK  = 128;              // threads per block (2 waves)
constexpr int NTILE  = 256;              // n-points per block (2 per thread)
constexpr int MTILE  = 128;              // m-points per block
constexpr int NTB    = NPTS / NTILE;     // 27
constexpr int MTB    = NPTS / MTILE;     // 54
constexpr int NBLK   = NTB * MTB;        // 1458

// exp(-0.1*d) = exp2(d * KEXP)
constexpr float KEXP  = -0.14426950408889634f;  // -0.1 * log2(e)
constexpr float M2K   = -2.0f * KEXP;           // scale for a-side geometry

// Layout of the 18 per-point values (b-side / LDS form):
//  0..2  xyz1 (unscaled)      3  K*|xyz1|^2
//  4..6  xyz2_t (unscaled)    7  K*|xyz2_t|^2
//  8..10 xyz2_gt (unscaled)  11  K*|xyz2_gt|^2
// 12..14 f1                  15..17 f2
__device__ __forceinline__ void point_data(
    int idx,
    const float* __restrict__ depth1, const float* __restrict__ depth2,
    const float* __restrict__ img1,   const float* __restrict__ img2,
    const float R[12], const float G[12], float o[18])
{
    const int u = idx % WIDTH;
    const int v = idx / WIDTH;
    const float gy = (float)u * (1.0f / 48.0f) - 1.0f;
    const float gz = (float)v * (1.0f / 36.0f) - 1.0f;
    const float d1 = depth1[idx];
    const float d2 = depth2[idx];
    const float x1 = d1, y1 = d1 * gy, z1 = d1 * gz;
    const float x2 = d2, y2 = d2 * gy, z2 = d2 * gz;
    const float xt = R[0] * x2 + R[1] * y2 + R[2]  * z2 + R[3];
    const float yt = R[4] * x2 + R[5] * y2 + R[6]  * z2 + R[7];
    const float zt = R[8] * x2 + R[9] * y2 + R[10] * z2 + R[11];
    const float xg = G[0] * x2 + G[1] * y2 + G[2]  * z2 + G[3];
    const float yg = G[4] * x2 + G[5] * y2 + G[6]  * z2 + G[7];
    const float zg = G[8] * x2 + G[9] * y2 + G[10] * z2 + G[11];

    o[0] = x1; o[1] = y1; o[2]  = z1; o[3]  = KEXP * (x1*x1 + y1*y1 + z1*z1);
    o[4] = xt; o[5] = yt; o[6]  = zt; o[7]  = KEXP * (xt*xt + yt*yt + zt*zt);
    o[8] = xg; o[9] = yg; o[10] = zg; o[11] = KEXP * (xg*xg + yg*yg + zg*zg);
    o[12] = img1[idx];
    o[13] = img1[NPTS + idx];
    o[14] = img1[2 * NPTS + idx];
    o[15] = img2[idx];
    o[16] = img2[NPTS + idx];
    o[17] = img2[2 * NPTS + idx];
}

__global__ __launch_bounds__(BLOCK) void pair_kernel(
    const float* __restrict__ depth1, const float* __restrict__ depth2,
    const float* __restrict__ pose,   const float* __restrict__ img1,
    const float* __restrict__ img2,   const float* __restrict__ poseg,
    double* __restrict__ partials)
{
    __shared__ float sm[MTILE][20];    // pad row to 80B -> 16B-aligned rows
    __shared__ double red[2][5];

    const int t  = threadIdx.x;
    const int bn = blockIdx.x % NTB;
    const int bm = blockIdx.x / NTB;

    float R[12], G[12];
#pragma unroll
    for (int i = 0; i < 12; ++i) { R[i] = pose[i]; G[i] = poseg[i]; }

    // stage m-tile into LDS (one point per thread)
    {
        float o[18];
        point_data(bm * MTILE + t, depth1, depth2, img1, img2, R, G, o);
#pragma unroll
        for (int k = 0; k < 18; ++k) sm[t][k] = o[k];
    }

    // two n-points per thread, packed as v2f; a-side geometry pre-scaled by -2K
    v2f A[18];
    {
        float o0[18], o1[18];
        point_data(bn * NTILE + t,         depth1, depth2, img1, img2, R, G, o0);
        point_data(bn * NTILE + BLOCK + t, depth1, depth2, img1, img2, R, G, o1);
#pragma unroll
        for (int k = 0; k < 18; ++k) { A[k].x = o0[k]; A[k].y = o1[k]; }
#pragma unroll
        for (int grp = 0; grp < 3; ++grp) {
#pragma unroll
            for (int k = 0; k < 3; ++k) A[grp * 4 + k] *= M2K;
        }
    }

    __syncthreads();

    v2f s0 = {0.f, 0.f}, s1 = s0, s2 = s0, s3 = s0, s4 = s0;

#pragma unroll 2
    for (int m = 0; m < MTILE; ++m) {
        const float* b = sm[m];   // wave-uniform -> LDS broadcast

        // exp args: K|a|^2 + K|b|^2 - 2K * (a . b), a-side pre-scaled
        v2f t11 = A[3] + b[3];
        t11 = A[0] * b[0] + t11;
        t11 = A[1] * b[1] + t11;
        t11 = A[2] * b[2] + t11;

        v2f t22 = A[7] + b[7];
        t22 = A[4] * b[4] + t22;
        t22 = A[5] * b[5] + t22;
        t22 = A[6] * b[6] + t22;

        v2f t12 = A[3] + b[7];
        t12 = A[0] * b[4] + t12;
        t12 = A[1] * b[5] + t12;
        t12 = A[2] * b[6] + t12;

        v2f tgg = A[11] + b[11];
        tgg = A[8]  * b[8]  + tgg;
        tgg = A[9]  * b[9]  + tgg;
        tgg = A[10] * b[10] + tgg;

        v2f t1g = A[3] + b[11];
        t1g = A[0] * b[8]  + t1g;
        t1g = A[1] * b[9]  + t1g;
        t1g = A[2] * b[10] + t1g;

        // feature grams
        v2f g11 = A[12] * b[12];
        g11 = A[13] * b[13] + g11;
        g11 = A[14] * b[14] + g11;
        v2f g22 = A[15] * b[15];
        g22 = A[16] * b[16] + g22;
        g22 = A[17] * b[17] + g22;
        v2f g12 = A[12] * b[15];
        g12 = A[13] * b[16] + g12;
        g12 = A[14] * b[17] + g12;

        v2f e11, e22, e12, egg, e1g;
        e11.x = __builtin_amdgcn_exp2f(t11.x); e11.y = __builtin_amdgcn_exp2f(t11.y);
        e22.x = __builtin_amdgcn_exp2f(t22.x); e22.y = __builtin_amdgcn_exp2f(t22.y);
        e12.x = __builtin_amdgcn_exp2f(t12.x); e12.y = __builtin_amdgcn_exp2f(t12.y);
        egg.x = __builtin_amdgcn_exp2f(tgg.x); egg.y = __builtin_amdgcn_exp2f(tgg.y);
        e1g.x = __builtin_amdgcn_exp2f(t1g.x); e1g.y = __builtin_amdgcn_exp2f(t1g.y);

        s0 = e11 * g11 + s0;
        s1 = e22 * g22 + s1;
        s2 = e12 * g12 + s2;
        s3 = egg * g22 + s3;
        s4 = e1g * g12 + s4;
    }

    // per-thread fold then 64-lane reduction (float), then double per wave
    float r0 = s0.x + s0.y, r1 = s1.x + s1.y, r2 = s2.x + s2.y,
          r3 = s3.x + s3.y, r4 = s4.x + s4.y;
#pragma unroll
    for (int off = 32; off > 0; off >>= 1) {
        r0 += __shfl_down(r0, off);
        r1 += __shfl_down(r1, off);
        r2 += __shfl_down(r2, off);
        r3 += __shfl_down(r3, off);
        r4 += __shfl_down(r4, off);
    }
    const int wave = t >> 6, lane = t & 63;
    if (lane == 0) {
        red[wave][0] = (double)r0; red[wave][1] = (double)r1;
        red[wave][2] = (double)r2; red[wave][3] = (double)r3;
        red[wave][4] = (double)r4;
    }
    __syncthreads();
    if (t == 0) {
        double* out = partials + (size_t)blockIdx.x * 5;
#pragma unroll
        for (int c = 0; c < 5; ++c)
            out[c] = red[0][c] + red[1][c];
    }
}

__global__ void finalize_kernel(const double* __restrict__ partials,
                                float* __restrict__ out)
{
    double l0 = 0, l1 = 0, l2 = 0, l3 = 0, l4 = 0;
    for (int b = threadIdx.x; b < NBLK; b += 64) {
        const double* p = partials + (size_t)b * 5;
        l0 += p[0]; l1 += p[1]; l2 += p[2]; l3 += p[3]; l4 += p[4];
    }
#pragma unroll
    for (int off = 32; off > 0; off >>= 1) {
        l0 += __shfl_down(l0, off);
        l1 += __shfl_down(l1, off);
        l2 += __shfl_down(l2, off);
        l3 += __shfl_down(l3, off);
        l4 += __shfl_down(l4, off);
    }
    if (threadIdx.x == 0) {
        const double num = l0 + l1 - 2.0 * l2;
        const double den = l0 + l3 - 2.0 * l4;
        out[0] = (float)(num / den);
    }
}

extern "C" void kernel_launch(void* const* d_in, const int* in_sizes, int n_in,
                              void* d_out, int out_size, void* d_ws, size_t ws_size,
                              hipStream_t stream)
{
    const float* depth1 = (const float*)d_in[0];
    const float* depth2 = (const float*)d_in[1];
    const float* pose   = (const float*)d_in[2];
    const float* img1   = (const float*)d_in[3];
    const float* img2   = (const float*)d_in[4];
    const float* poseg  = (const float*)d_in[5];

    double* partials = (double*)d_ws;   // NBLK*5 doubles = ~57 KB

    pair_kernel<<<NBLK, BLOCK, 0, stream>>>(depth1, depth2, pose, img1, img2,
                                            poseg, partials);
    finalize_kernel<<<1, 64, 0, stream>>>(partials, (float*)d_out);
}